// Round 5
// baseline (689.444 us; speedup 1.0000x reference)
//
#include <hip/hip_runtime.h>

typedef __bf16 bf16x8 __attribute__((ext_vector_type(8)));
typedef float f32x4 __attribute__((ext_vector_type(4)));

static __device__ __forceinline__ unsigned short f2bf(float f) {
    unsigned u = __builtin_bit_cast(unsigned, f);
    unsigned r = u + 0x7fffu + ((u >> 16) & 1u);   // RNE; inputs finite
    return (unsigned short)(r >> 16);
}

#define GLD_LDS16(g, l) __builtin_amdgcn_global_load_lds( \
    (const __attribute__((address_space(1))) unsigned int*)(const void*)(g), \
    (__attribute__((address_space(3))) unsigned int*)(void*)(l), 16, 0, 0)

// ---------------- K1: all independent prep work, region-per-block -------------
// regions: [0,2048) W4 cvt | [2048,4548) Wout cvt | [4548,5556) emb gather |
//          [5556,6181) out zeros | [6181,6246) ps+ctrs | [6246,6758) mean
__global__ __launch_bounds__(256) void k_prep(
    const float* Wih, const float* Whh, const float* Wh, const float* Wc,
    const float* Wout, const float* emb, const int* targets, const float* enc,
    unsigned short* Wih_b, unsigned short* Whh_b, unsigned short* Wh_b,
    unsigned short* Wc_b, unsigned short* Wout_b, unsigned short* Aemb,
    float* out, int* ctrs, float* ps, unsigned short* mean_b)
{
    const int bid = blockIdx.x, tid = threadIdx.x;

    if (bid < 2048) {                      // Wih/Whh/Wh/Wc: 4 x 1048576 floats
        long f = ((long)bid * 256 + tid) * 8;
        int a = (int)(f >> 20);
        long off = f & 1048575;
        const float* s = (a == 0) ? Wih : (a == 1) ? Whh : (a == 2) ? Wh : Wc;
        unsigned short* d = (a == 0) ? Wih_b : (a == 1) ? Whh_b : (a == 2) ? Wh_b : Wc_b;
        float4 v0 = *(const float4*)(s + off);
        float4 v1 = *(const float4*)(s + off + 4);
        unsigned short r[8] = {f2bf(v0.x), f2bf(v0.y), f2bf(v0.z), f2bf(v0.w),
                               f2bf(v1.x), f2bf(v1.y), f2bf(v1.z), f2bf(v1.w)};
        *(uint4*)(d + off) = *(uint4*)r;
        return;
    }
    if (bid < 4548) {                      // Wout: 5,120,000 floats (exact)
        long f = ((long)(bid - 2048) * 256 + tid) * 8;
        float4 v0 = *(const float4*)(Wout + f);
        float4 v1 = *(const float4*)(Wout + f + 4);
        unsigned short r[8] = {f2bf(v0.x), f2bf(v0.y), f2bf(v0.z), f2bf(v0.w),
                               f2bf(v1.x), f2bf(v1.y), f2bf(v1.z), f2bf(v1.w)};
        *(uint4*)(Wout_b + f) = *(uint4*)r;
        return;
    }
    if (bid < 5556) {                      // gather: 4032 rows x 512 (exact)
        unsigned t = (unsigned)(bid - 4548) * 256 + tid;   // < 258048
        unsigned row = t >> 6;                             // 64 threads/row
        unsigned col = (t & 63) * 8;
        unsigned b = row / 63u, tt = row - b * 63u;
        int trg = targets[b * 64 + tt];
        const float* s = emb + (long)trg * 512 + col;
        float4 v0 = *(const float4*)(s);
        float4 v1 = *(const float4*)(s + 4);
        unsigned short r[8] = {f2bf(v0.x), f2bf(v0.y), f2bf(v0.z), f2bf(v0.w),
                               f2bf(v1.x), f2bf(v1.y), f2bf(v1.z), f2bf(v1.w)};
        *(uint4*)(Aemb + (long)row * 512 + col) = *(uint4*)r;
        return;
    }
    if (bid < 6181) {                      // zero out[:,0,:]: 640,000 floats (exact)
        unsigned idx = ((unsigned)(bid - 5556) * 256 + tid) * 4;
        unsigned b = idx / 10000u, v = idx - b * 10000u;
        *(float4*)(out + (long)b * 640000 + v) = (float4){0.f, 0.f, 0.f, 0.f};
        return;
    }
    if (bid < 6246) {                      // ps zeros (64 blocks) + ctrs (1 block)
        int rel = bid - 6181;
        if (rel < 64) {
            unsigned idx = ((unsigned)rel * 256 + tid) * 4;
            *(float4*)(ps + idx) = (float4){0.f, 0.f, 0.f, 0.f};
        } else {
            ctrs[tid] = 0;
        }
        return;
    }
    {                                      // mean over P=196 -> bf16 [64][2048]
        unsigned idx = (unsigned)(bid - 6246) * 256 + tid;  // < 131072
        unsigned b = idx >> 11, c = idx & 2047;
        const float* base = enc + (long)b * 196 * 2048 + c;
        float s0 = 0.f, s1 = 0.f, s2 = 0.f, s3 = 0.f;
        for (int p = 0; p < 196; p += 4) {
            s0 += base[(long)(p + 0) * 2048];
            s1 += base[(long)(p + 1) * 2048];
            s2 += base[(long)(p + 2) * 2048];
            s3 += base[(long)(p + 3) * 2048];
        }
        mean_b[(long)b * 2048 + c] = f2bf((s0 + s1 + s2 + s3) * (1.f / 196.f));
    }
}

// ---------------- K2: h0c0 partials (blocks 0..63) + xg GEMM (64..575) --------
__global__ __launch_bounds__(256) void k_gemm2(
    const unsigned short* mean_b, const unsigned short* Whb, const unsigned short* Wcb,
    float* ps,
    const unsigned short* Aemb, const unsigned short* Wihb,
    const float* bih, const float* bhh, float* xg)
{
    __shared__ __align__(16) char smem[16384];
    const int bid = blockIdx.x, tid = threadIdx.x;
    const int w = tid >> 6, lane = tid & 63, quad = lane >> 4, l16 = lane & 15;

    if (bid < 64) {
        // ---- h0/c0 partials: split-K x4, fp32 atomic accumulate ----
        unsigned short* As = (unsigned short*)smem;            // 64*40*2 = 5120
        unsigned short* Bs = (unsigned short*)(smem + 5120);
        const int n0 = (bid & 15) * 64;
        const int kc = (bid >> 4) * 16;
        const int r = tid >> 2, seg = tid & 3;
        f32x4 acc[4];
#pragma unroll
        for (int i = 0; i < 4; i++) acc[i] = (f32x4){0.f, 0.f, 0.f, 0.f};

        for (int kb = kc; kb < kc + 16; kb++) {
            int k0 = kb * 32;
            *(uint4*)&As[r * 40 + seg * 8] = *(const uint4*)&mean_b[(long)r * 2048 + k0 + seg * 8];
            int ngr = n0 + r;
            const unsigned short* bsrc = (ngr < 512) ? (Whb + (long)ngr * 2048)
                                                     : (Wcb + (long)(ngr - 512) * 2048);
            *(uint4*)&Bs[r * 40 + seg * 8] = *(const uint4*)&bsrc[k0 + seg * 8];
            __syncthreads();
            bf16x8 bfr = *(const bf16x8*)&Bs[(16 * w + l16) * 40 + quad * 8];
#pragma unroll
            for (int mt = 0; mt < 4; mt++) {
                bf16x8 af = *(const bf16x8*)&As[(mt * 16 + l16) * 40 + quad * 8];
                acc[mt] = __builtin_amdgcn_mfma_f32_16x16x32_bf16(af, bfr, acc[mt], 0, 0, 0);
            }
            __syncthreads();
        }
        int ng = n0 + 16 * w + l16;
#pragma unroll
        for (int mt = 0; mt < 4; mt++) {
#pragma unroll
            for (int rr = 0; rr < 4; rr++) {
                int m = mt * 16 + quad * 4 + rr;
                atomicAdd(&ps[(long)m * 1024 + ng], acc[mt][rr]);
            }
        }
        return;
    }

    // ---- xg: [4032x512] @ [2048x512]^T + biases, m97-style 128x128 tile ----
    unsigned short* As = (unsigned short*)smem;                // 128*32*2 = 8192
    unsigned short* Bs = (unsigned short*)(smem + 8192);
    const int rel = bid - 64;
    const int n0 = (rel & 15) * 128, m0 = (rel >> 4) * 128;
    const int wm = w >> 1, wn = w & 1;
    const int gr = lane >> 2, gc = (lane & 3) * 8;

    f32x4 acc[4][4];
#pragma unroll
    for (int i = 0; i < 4; i++)
#pragma unroll
        for (int j = 0; j < 4; j++) acc[i][j] = (f32x4){0.f, 0.f, 0.f, 0.f};

    for (int kb = 0; kb < 16; kb++) {
        int k0 = kb * 32;
#pragma unroll
        for (int p = 0; p < 2; p++) {
            int rowa = m0 + p * 64 + w * 16 + gr;
            GLD_LDS16(Aemb + (long)rowa * 512 + k0 + gc, As + (p * 64 + w * 16) * 32);
            int rowb = n0 + p * 64 + w * 16 + gr;
            GLD_LDS16(Wihb + (long)rowb * 512 + k0 + gc, Bs + (p * 64 + w * 16) * 32);
        }
        __syncthreads();
        bf16x8 af[4], bf[4];
#pragma unroll
        for (int mt = 0; mt < 4; mt++)
            af[mt] = *(const bf16x8*)&As[(wm * 64 + mt * 16 + l16) * 32 + quad * 8];
#pragma unroll
        for (int nt = 0; nt < 4; nt++)
            bf[nt] = *(const bf16x8*)&Bs[(wn * 64 + nt * 16 + l16) * 32 + quad * 8];
#pragma unroll
        for (int mt = 0; mt < 4; mt++)
#pragma unroll
            for (int nt = 0; nt < 4; nt++)
                acc[mt][nt] = __builtin_amdgcn_mfma_f32_16x16x32_bf16(af[mt], bf[nt], acc[mt][nt], 0, 0, 0);
        __syncthreads();
    }
#pragma unroll
    for (int nt = 0; nt < 4; nt++) {
        int n = n0 + wn * 64 + nt * 16 + l16;
        float bias = bih[n] + bhh[n];
#pragma unroll
        for (int mt = 0; mt < 4; mt++) {
#pragma unroll
            for (int rr = 0; rr < 4; rr++) {
                int r = m0 + wm * 64 + mt * 16 + quad * 4 + rr;
                if (r < 4032) xg[(long)r * 2048 + n] = acc[mt][nt][rr] + bias;
            }
        }
    }
}

// ---------------- scan: R0-proven lockstep + fused h0/c0 finalize -------------
// Prologue computes h0 (tanh(ps+bh), bitwise-identical f2bf) directly into the
// hs staging buffer and c0 into registers; step s==1 skips the global staging.
// Hbuf[0] is never written (nothing reads it). Protocol otherwise untouched.
__global__ __launch_bounds__(256, 1) void k_scan(
    const unsigned short* Whh_b, const float* xg,
    const float* ps, const float* bh, const float* bc,
    unsigned short* Hbuf, int* ctrs)
{
    __shared__ unsigned short Wlds[128 * 520];  // 130 KB resident W_hh slice
    __shared__ unsigned short hs[16 * 520];     // staged h[s-1] (16 batches x 512)
    __shared__ float gs[16 * 133];              // gate exchange
    const int tid = threadIdx.x;
    const int gid = blockIdx.x;
    const int b0 = (gid & 3) * 16;   // batch group
    const int j0 = (gid >> 2) * 32;  // hidden-unit slice
    const int w = tid >> 6, lane = tid & 63, quad = lane >> 4, l16 = lane & 15;
    const int m = tid >> 4, u0 = (tid & 15) * 2;

    // resident W_hh slice: rows nrel = q*32+u  <->  W_hh row q*512 + j0 + u
    for (int nrel = w; nrel < 128; nrel += 4) {
        int q = nrel >> 5, u = nrel & 31;
        *(uint4*)&Wlds[nrel * 520 + lane * 8] =
            *(const uint4*)&Whh_b[(long)(q * 512 + j0 + u) * 512 + lane * 8];
    }
    // fused k_fin: h0 rows for this batch group -> hs (same bits as old path)
    {
        int j = tid >> 4;                 // batch 0..15
        int ub = (tid & 15) * 32;         // unit base
        const float* prow = ps + (long)(b0 + j) * 1024;
#pragma unroll
        for (int q = 0; q < 4; q++) {
            float4 a  = *(const float4*)(prow + ub + q * 8);
            float4 b  = *(const float4*)(prow + ub + q * 8 + 4);
            float4 ba = *(const float4*)(bh + ub + q * 8);
            float4 bb = *(const float4*)(bh + ub + q * 8 + 4);
            unsigned short r[8] = {
                f2bf(tanhf(a.x + ba.x)), f2bf(tanhf(a.y + ba.y)),
                f2bf(tanhf(a.z + ba.z)), f2bf(tanhf(a.w + ba.w)),
                f2bf(tanhf(b.x + bb.x)), f2bf(tanhf(b.y + bb.y)),
                f2bf(tanhf(b.z + bb.z)), f2bf(tanhf(b.w + bb.w))};
            *(uint4*)&hs[j * 520 + ub + q * 8] = *(uint4*)r;
        }
    }
    // fused k_fin: c0 for own slice
    float c0v, c1v;
    {
        float2 pc  = *(const float2*)&ps[(long)(b0 + m) * 1024 + 512 + j0 + u0];
        float2 bcv = *(const float2*)&bc[j0 + u0];
        c0v = tanhf(pc.x + bcv.x);
        c1v = tanhf(pc.y + bcv.y);
    }
    int* ctr = ctrs + (gid & 3) * 64;
    __syncthreads();

    for (int s = 1; s < 64; s++) {
        // xg prefetch (read-only, normal cached loads)
        const float* xb = xg + ((long)(b0 + m) * 63 + (s - 1)) * 2048 + j0 + u0;
        float2 xv0 = *(const float2*)(xb + 0);
        float2 xv1 = *(const float2*)(xb + 512);
        float2 xv2 = *(const float2*)(xb + 1024);
        float2 xv3 = *(const float2*)(xb + 1536);

        if (s > 1) {
            // coherent staging of h[s-1]: 16 rows x 256 dwords, round j = row j
            const unsigned* hsrc = (const unsigned*)(Hbuf + ((long)(s - 1) * 64 + b0) * 512);
            unsigned hv[16];
#pragma unroll
            for (int j = 0; j < 16; j++)
                hv[j] = __hip_atomic_load(hsrc + j * 256 + tid, __ATOMIC_RELAXED,
                                          __HIP_MEMORY_SCOPE_AGENT);
#pragma unroll
            for (int j = 0; j < 16; j++)
                *(unsigned*)&hs[j * 520 + tid * 2] = hv[j];
        }
        __syncthreads();

        f32x4 acc0 = (f32x4){0.f, 0.f, 0.f, 0.f};
        f32x4 acc1 = (f32x4){0.f, 0.f, 0.f, 0.f};
#pragma unroll
        for (int kk = 0; kk < 16; kk++) {
            bf16x8 a  = *(const bf16x8*)&hs[l16 * 520 + kk * 32 + quad * 8];
            bf16x8 bA = *(const bf16x8*)&Wlds[(32 * w + l16) * 520 + kk * 32 + quad * 8];
            bf16x8 bB = *(const bf16x8*)&Wlds[(32 * w + 16 + l16) * 520 + kk * 32 + quad * 8];
            acc0 = __builtin_amdgcn_mfma_f32_16x16x32_bf16(a, bA, acc0, 0, 0, 0);
            acc1 = __builtin_amdgcn_mfma_f32_16x16x32_bf16(a, bB, acc1, 0, 0, 0);
        }
#pragma unroll
        for (int rr = 0; rr < 4; rr++) {
            gs[(quad * 4 + rr) * 133 + 32 * w + l16] = acc0[rr];
            gs[(quad * 4 + rr) * 133 + 32 * w + 16 + l16] = acc1[rr];
        }
        __syncthreads();

        float gi0 = gs[m * 133 + u0]          + xv0.x;
        float gi1 = gs[m * 133 + u0 + 1]      + xv0.y;
        float gf0 = gs[m * 133 + 32 + u0]     + xv1.x;
        float gf1 = gs[m * 133 + 33 + u0]     + xv1.y;
        float gg0 = gs[m * 133 + 64 + u0]     + xv2.x;
        float gg1 = gs[m * 133 + 65 + u0]     + xv2.y;
        float go0 = gs[m * 133 + 96 + u0]     + xv3.x;
        float go1 = gs[m * 133 + 97 + u0]     + xv3.y;
        float cn0 = (1.f / (1.f + __expf(-gf0))) * c0v + (1.f / (1.f + __expf(-gi0))) * tanhf(gg0);
        float cn1 = (1.f / (1.f + __expf(-gf1))) * c1v + (1.f / (1.f + __expf(-gi1))) * tanhf(gg1);
        c0v = cn0; c1v = cn1;
        float h0v = (1.f / (1.f + __expf(-go0))) * tanhf(cn0);
        float h1v = (1.f / (1.f + __expf(-go1))) * tanhf(cn1);
        unsigned hp = (unsigned)f2bf(h0v) | ((unsigned)f2bf(h1v) << 16);
        __hip_atomic_store((unsigned*)(Hbuf + ((long)s * 64 + b0 + m) * 512 + j0 + u0), hp,
                           __ATOMIC_RELAXED, __HIP_MEMORY_SCOPE_AGENT);

        if (s < 63) {
            __syncthreads();   // all waves' h stores drained (vmcnt 0) before count
            if (tid == 0) {
                __hip_atomic_fetch_add(ctr, 1, __ATOMIC_RELEASE, __HIP_MEMORY_SCOPE_AGENT);
                int target = s * 16;
                while (__hip_atomic_load(ctr, __ATOMIC_RELAXED, __HIP_MEMORY_SCOPE_AGENT) < target) {}
            }
            __syncthreads();
        }
    }
}

// ---------------- logits: 2 m-tiles/block share B; XCD-chunked, m fastest -----
__global__ __launch_bounds__(256) void k_out(
    const unsigned short* A, const unsigned short* Wob, const float* bout, float* out)
{
    __shared__ unsigned short As[2][128 * 32];
    __shared__ unsigned short Bs[128 * 32];
    const int tid = threadIdx.x;
    // 1264 tiles = 8 XCDs x 158 (exact); m fastest: Wout panel L2-resident
    const int tile = (blockIdx.x & 7) * 158 + (blockIdx.x >> 3);
    const int n0 = (tile >> 4) * 128;      // 79 n-tiles
    const int m0 = (tile & 15) * 256;      // 16 m-pairs
    const int w = tid >> 6, lane = tid & 63, quad = lane >> 4, l16 = lane & 15;
    const int wm = w >> 1, wn = w & 1;
    const int gr = lane >> 2, gc = (lane & 3) * 8;

    f32x4 acc[2][4][4];
#pragma unroll
    for (int h = 0; h < 2; h++)
#pragma unroll
        for (int i = 0; i < 4; i++)
#pragma unroll
            for (int j = 0; j < 4; j++) acc[h][i][j] = (f32x4){0.f, 0.f, 0.f, 0.f};

    for (int kb = 0; kb < 16; kb++) {
        int k0 = kb * 32;
#pragma unroll
        for (int p = 0; p < 2; p++) {
            int rowb = n0 + p * 64 + w * 16 + gr;
            GLD_LDS16(Wob + (long)rowb * 512 + k0 + gc, Bs + (p * 64 + w * 16) * 32);
#pragma unroll
            for (int h = 0; h < 2; h++) {
                int rowa = m0 + h * 128 + p * 64 + w * 16 + gr;
                GLD_LDS16(A + (long)rowa * 512 + k0 + gc, As[h] + (p * 64 + w * 16) * 32);
            }
        }
        __syncthreads();
        bf16x8 bf[4];
#pragma unroll
        for (int nt = 0; nt < 4; nt++)
            bf[nt] = *(const bf16x8*)&Bs[(wn * 64 + nt * 16 + l16) * 32 + quad * 8];
#pragma unroll
        for (int h = 0; h < 2; h++) {
#pragma unroll
            for (int mt = 0; mt < 4; mt++) {
                bf16x8 af = *(const bf16x8*)&As[h][(wm * 64 + mt * 16 + l16) * 32 + quad * 8];
#pragma unroll
                for (int nt = 0; nt < 4; nt++)
                    acc[h][mt][nt] = __builtin_amdgcn_mfma_f32_16x16x32_bf16(af, bf[nt], acc[h][mt][nt], 0, 0, 0);
            }
        }
        __syncthreads();
    }
#pragma unroll
    for (int h = 0; h < 2; h++) {
#pragma unroll
        for (int nt = 0; nt < 4; nt++) {
            int n = n0 + wn * 64 + nt * 16 + l16;
            if (n >= 10000) continue;
            float bias = bout[n];
#pragma unroll
            for (int mt = 0; mt < 4; mt++) {
#pragma unroll
                for (int rr = 0; rr < 4; rr++) {
                    int r = m0 + h * 128 + wm * 64 + mt * 16 + quad * 4 + rr;  // A row
                    if (r < 4032) {
                        int s = (r >> 6) + 1, b = r & 63;
                        out[((long)b * 64 + s) * 10000 + n] = acc[h][mt][nt][rr] + bias;
                    }
                }
            }
        }
    }
}

extern "C" void kernel_launch(void* const* d_in, const int* in_sizes, int n_in,
                              void* d_out, int out_size, void* d_ws, size_t ws_size,
                              hipStream_t stream)
{
    const float* enc     = (const float*)d_in[0];
    const int*   targets = (const int*)d_in[1];
    const float* emb     = (const float*)d_in[2];
    const float* Wih     = (const float*)d_in[3];
    const float* Whh     = (const float*)d_in[4];
    const float* bih     = (const float*)d_in[5];
    const float* bhh     = (const float*)d_in[6];
    const float* Wh      = (const float*)d_in[7];
    const float* bh      = (const float*)d_in[8];
    const float* Wc      = (const float*)d_in[9];
    const float* bc      = (const float*)d_in[10];
    const float* Wout    = (const float*)d_in[11];
    const float* bout    = (const float*)d_in[12];
    float* out = (float*)d_out;

    char* ws = (char*)d_ws;
    size_t off = 0;
    auto alloc = [&](size_t bytes) {
        void* p = ws + off;
        off = (off + bytes + 255) & ~(size_t)255;
        return p;
    };
    unsigned short* mean_b = (unsigned short*)alloc((size_t)64 * 2048 * 2);
    unsigned short* Wih_b  = (unsigned short*)alloc((size_t)2048 * 512 * 2);
    unsigned short* Whh_b  = (unsigned short*)alloc((size_t)2048 * 512 * 2);
    unsigned short* Wh_b   = (unsigned short*)alloc((size_t)512 * 2048 * 2);
    unsigned short* Wc_b   = (unsigned short*)alloc((size_t)512 * 2048 * 2);
    unsigned short* Wout_b = (unsigned short*)alloc((size_t)10000 * 512 * 2);
    // +64 pad rows: 128-row staging tiles overread past row 4032 harmlessly
    unsigned short* Aemb   = (unsigned short*)alloc((size_t)(4032 + 64) * 512 * 2);
    float*          xg     = (float*)alloc((size_t)4032 * 2048 * 4);
    // +64 pad rows: k_out's A view (Hbuf+64*512) staging reads up to row 4095
    unsigned short* Hbuf   = (unsigned short*)alloc((size_t)(64 * 64 + 64) * 512 * 2);
    int*            ctrs   = (int*)alloc(256 * 4);
    float*          ps     = (float*)alloc((size_t)64 * 1024 * 4);

    k_prep<<<6758, 256, 0, stream>>>(Wih, Whh, Wh, Wc, Wout, emb, targets, enc,
                                     Wih_b, Whh_b, Wh_b, Wc_b, Wout_b, Aemb,
                                     out, ctrs, ps, mean_b);
    k_gemm2<<<576, 256, 0, stream>>>(mean_b, Wh_b, Wc_b, ps,
                                     Aemb, Wih_b, bih, bhh, xg);
    k_scan<<<64, 256, 0, stream>>>(Whh_b, xg, ps, bh, bc, Hbuf, ctrs);
    k_out<<<1264, 256, 0, stream>>>(Hbuf + 64 * 512, Wout_b, bout, out);
}

// Round 6
// 617.805 us; speedup vs baseline: 1.1160x; 1.1160x over previous
//
#include <hip/hip_runtime.h>

typedef __bf16 bf16x8 __attribute__((ext_vector_type(8)));
typedef float f32x4 __attribute__((ext_vector_type(4)));

static __device__ __forceinline__ unsigned short f2bf(float f) {
    unsigned u = __builtin_bit_cast(unsigned, f);
    unsigned r = u + 0x7fffu + ((u >> 16) & 1u);   // RNE; inputs finite
    return (unsigned short)(r >> 16);
}

#define GLD_LDS16(g, l) __builtin_amdgcn_global_load_lds( \
    (const __attribute__((address_space(1))) unsigned int*)(const void*)(g), \
    (__attribute__((address_space(3))) unsigned int*)(void*)(l), 16, 0, 0)

// ---------------- K1: prep work needed BEFORE gemm2/scan ----------------------
// regions: [0,2048) W4 cvt | [2048,3056) emb gather | [3056,3121) ps+ctrs |
//          [3121,3633) mean          (Wout cvt + out zeros moved to scan shadow)
__global__ __launch_bounds__(256) void k_prep(
    const float* Wih, const float* Whh, const float* Wh, const float* Wc,
    const float* emb, const int* targets, const float* enc,
    unsigned short* Wih_b, unsigned short* Whh_b, unsigned short* Wh_b,
    unsigned short* Wc_b, unsigned short* Aemb,
    int* ctrs, float* ps, unsigned short* mean_b)
{
    const int bid = blockIdx.x, tid = threadIdx.x;

    if (bid < 2048) {                      // Wih/Whh/Wh/Wc: 4 x 1048576 floats
        long f = ((long)bid * 256 + tid) * 8;
        int a = (int)(f >> 20);
        long off = f & 1048575;
        const float* s = (a == 0) ? Wih : (a == 1) ? Whh : (a == 2) ? Wh : Wc;
        unsigned short* d = (a == 0) ? Wih_b : (a == 1) ? Whh_b : (a == 2) ? Wh_b : Wc_b;
        float4 v0 = *(const float4*)(s + off);
        float4 v1 = *(const float4*)(s + off + 4);
        unsigned short r[8] = {f2bf(v0.x), f2bf(v0.y), f2bf(v0.z), f2bf(v0.w),
                               f2bf(v1.x), f2bf(v1.y), f2bf(v1.z), f2bf(v1.w)};
        *(uint4*)(d + off) = *(uint4*)r;
        return;
    }
    if (bid < 3056) {                      // gather: 4032 rows x 512 (exact)
        unsigned t = (unsigned)(bid - 2048) * 256 + tid;   // < 258048
        unsigned row = t >> 6;                             // 64 threads/row
        unsigned col = (t & 63) * 8;
        unsigned b = row / 63u, tt = row - b * 63u;
        int trg = targets[b * 64 + tt];
        const float* s = emb + (long)trg * 512 + col;
        float4 v0 = *(const float4*)(s);
        float4 v1 = *(const float4*)(s + 4);
        unsigned short r[8] = {f2bf(v0.x), f2bf(v0.y), f2bf(v0.z), f2bf(v0.w),
                               f2bf(v1.x), f2bf(v1.y), f2bf(v1.z), f2bf(v1.w)};
        *(uint4*)(Aemb + (long)row * 512 + col) = *(uint4*)r;
        return;
    }
    if (bid < 3121) {                      // ps zeros (64 blocks) + ctrs (1 block)
        int rel = bid - 3056;
        if (rel < 64) {
            unsigned idx = ((unsigned)rel * 256 + tid) * 4;
            *(float4*)(ps + idx) = (float4){0.f, 0.f, 0.f, 0.f};
        } else {
            ctrs[tid] = 0;
        }
        return;
    }
    {                                      // mean over P=196 -> bf16 [64][2048]
        unsigned idx = (unsigned)(bid - 3121) * 256 + tid;  // < 131072
        unsigned b = idx >> 11, c = idx & 2047;
        const float* base = enc + (long)b * 196 * 2048 + c;
        float s0 = 0.f, s1 = 0.f, s2 = 0.f, s3 = 0.f;
        for (int p = 0; p < 196; p += 4) {
            s0 += base[(long)(p + 0) * 2048];
            s1 += base[(long)(p + 1) * 2048];
            s2 += base[(long)(p + 2) * 2048];
            s3 += base[(long)(p + 3) * 2048];
        }
        mean_b[(long)b * 2048 + c] = f2bf((s0 + s1 + s2 + s3) * (1.f / 196.f));
    }
}

// ---------------- K2: h0c0 partials (blocks 0..63) + xg GEMM (64..575) --------
__global__ __launch_bounds__(256) void k_gemm2(
    const unsigned short* mean_b, const unsigned short* Whb, const unsigned short* Wcb,
    float* ps,
    const unsigned short* Aemb, const unsigned short* Wihb,
    const float* bih, const float* bhh, float* xg)
{
    __shared__ __align__(16) char smem[16384];
    const int bid = blockIdx.x, tid = threadIdx.x;
    const int w = tid >> 6, lane = tid & 63, quad = lane >> 4, l16 = lane & 15;

    if (bid < 64) {
        // ---- h0/c0 partials: split-K x4, fp32 atomic accumulate ----
        unsigned short* As = (unsigned short*)smem;            // 64*40*2 = 5120
        unsigned short* Bs = (unsigned short*)(smem + 5120);
        const int n0 = (bid & 15) * 64;
        const int kc = (bid >> 4) * 16;
        const int r = tid >> 2, seg = tid & 3;
        f32x4 acc[4];
#pragma unroll
        for (int i = 0; i < 4; i++) acc[i] = (f32x4){0.f, 0.f, 0.f, 0.f};

        for (int kb = kc; kb < kc + 16; kb++) {
            int k0 = kb * 32;
            *(uint4*)&As[r * 40 + seg * 8] = *(const uint4*)&mean_b[(long)r * 2048 + k0 + seg * 8];
            int ngr = n0 + r;
            const unsigned short* bsrc = (ngr < 512) ? (Whb + (long)ngr * 2048)
                                                     : (Wcb + (long)(ngr - 512) * 2048);
            *(uint4*)&Bs[r * 40 + seg * 8] = *(const uint4*)&bsrc[k0 + seg * 8];
            __syncthreads();
            bf16x8 bfr = *(const bf16x8*)&Bs[(16 * w + l16) * 40 + quad * 8];
#pragma unroll
            for (int mt = 0; mt < 4; mt++) {
                bf16x8 af = *(const bf16x8*)&As[(mt * 16 + l16) * 40 + quad * 8];
                acc[mt] = __builtin_amdgcn_mfma_f32_16x16x32_bf16(af, bfr, acc[mt], 0, 0, 0);
            }
            __syncthreads();
        }
        int ng = n0 + 16 * w + l16;
#pragma unroll
        for (int mt = 0; mt < 4; mt++) {
#pragma unroll
            for (int rr = 0; rr < 4; rr++) {
                int m = mt * 16 + quad * 4 + rr;
                atomicAdd(&ps[(long)m * 1024 + ng], acc[mt][rr]);
            }
        }
        return;
    }

    // ---- xg: [4032x512] @ [2048x512]^T + biases, m97-style 128x128 tile ----
    unsigned short* As = (unsigned short*)smem;                // 128*32*2 = 8192
    unsigned short* Bs = (unsigned short*)(smem + 8192);
    const int rel = bid - 64;
    const int n0 = (rel & 15) * 128, m0 = (rel >> 4) * 128;
    const int wm = w >> 1, wn = w & 1;
    const int gr = lane >> 2, gc = (lane & 3) * 8;

    f32x4 acc[4][4];
#pragma unroll
    for (int i = 0; i < 4; i++)
#pragma unroll
        for (int j = 0; j < 4; j++) acc[i][j] = (f32x4){0.f, 0.f, 0.f, 0.f};

    for (int kb = 0; kb < 16; kb++) {
        int k0 = kb * 32;
#pragma unroll
        for (int p = 0; p < 2; p++) {
            int rowa = m0 + p * 64 + w * 16 + gr;
            GLD_LDS16(Aemb + (long)rowa * 512 + k0 + gc, As + (p * 64 + w * 16) * 32);
            int rowb = n0 + p * 64 + w * 16 + gr;
            GLD_LDS16(Wihb + (long)rowb * 512 + k0 + gc, Bs + (p * 64 + w * 16) * 32);
        }
        __syncthreads();
        bf16x8 af[4], bf[4];
#pragma unroll
        for (int mt = 0; mt < 4; mt++)
            af[mt] = *(const bf16x8*)&As[(wm * 64 + mt * 16 + l16) * 32 + quad * 8];
#pragma unroll
        for (int nt = 0; nt < 4; nt++)
            bf[nt] = *(const bf16x8*)&Bs[(wn * 64 + nt * 16 + l16) * 32 + quad * 8];
#pragma unroll
        for (int mt = 0; mt < 4; mt++)
#pragma unroll
            for (int nt = 0; nt < 4; nt++)
                acc[mt][nt] = __builtin_amdgcn_mfma_f32_16x16x32_bf16(af[mt], bf[nt], acc[mt][nt], 0, 0, 0);
        __syncthreads();
    }
#pragma unroll
    for (int nt = 0; nt < 4; nt++) {
        int n = n0 + wn * 64 + nt * 16 + l16;
        float bias = bih[n] + bhh[n];
#pragma unroll
        for (int mt = 0; mt < 4; mt++) {
#pragma unroll
            for (int rr = 0; rr < 4; rr++) {
                int r = m0 + wm * 64 + mt * 16 + quad * 4 + rr;
                if (r < 4032) xg[(long)r * 2048 + n] = acc[mt][nt][rr] + bias;
            }
        }
    }
}

// ---------------- scan (blocks 0..63) + SHADOW copy work (blocks 64+) ---------
// Scan: R0-proven lockstep + fused h0/c0 finalize (R5-verified, 198 us).
// Shadow blocks do k_out-only prep (Wout cvt, out[:,0,:] zeros) on CUs the scan
// can't use: the 158KB static LDS forces 1 block/CU for ALL blocks, so shadow
// work is CU-isolated from the scan; only brief HBM/L2 overlap (~33 MB).
// No sync interaction in either direction; shadow blocks always terminate.
__global__ __launch_bounds__(256, 1) void k_scan(
    const unsigned short* Whh_b, const float* xg,
    const float* ps, const float* bh, const float* bc,
    unsigned short* Hbuf, int* ctrs,
    const float* Wout, unsigned short* Wout_b, float* out)
{
    __shared__ unsigned short Wlds[128 * 520];  // 130 KB resident W_hh slice
    __shared__ unsigned short hs[16 * 520];     // staged h[s-1] (16 batches x 512)
    __shared__ float gs[16 * 133];              // gate exchange
    const int tid = threadIdx.x;
    const int gid = blockIdx.x;

    if (gid >= 64) {
        // ================= shadow path =================
        int sb = gid - 64;
        if (sb < 2500) {                   // Wout cvt: 5,120,000 floats (exact)
            long f = ((long)sb * 256 + tid) * 8;
            float4 v0 = *(const float4*)(Wout + f);
            float4 v1 = *(const float4*)(Wout + f + 4);
            unsigned short r[8] = {f2bf(v0.x), f2bf(v0.y), f2bf(v0.z), f2bf(v0.w),
                                   f2bf(v1.x), f2bf(v1.y), f2bf(v1.z), f2bf(v1.w)};
            *(uint4*)(Wout_b + f) = *(uint4*)r;
        } else {                           // zero out[:,0,:]: 640,000 floats (exact)
            unsigned idx = ((unsigned)(sb - 2500) * 256 + tid) * 4;
            unsigned b = idx / 10000u, v = idx - b * 10000u;
            *(float4*)(out + (long)b * 640000 + v) = (float4){0.f, 0.f, 0.f, 0.f};
        }
        return;
    }

    // ================= scan path =================
    const int b0 = (gid & 3) * 16;   // batch group
    const int j0 = (gid >> 2) * 32;  // hidden-unit slice
    const int w = tid >> 6, lane = tid & 63, quad = lane >> 4, l16 = lane & 15;
    const int m = tid >> 4, u0 = (tid & 15) * 2;

    // resident W_hh slice: rows nrel = q*32+u  <->  W_hh row q*512 + j0 + u
    for (int nrel = w; nrel < 128; nrel += 4) {
        int q = nrel >> 5, u = nrel & 31;
        *(uint4*)&Wlds[nrel * 520 + lane * 8] =
            *(const uint4*)&Whh_b[(long)(q * 512 + j0 + u) * 512 + lane * 8];
    }
    // fused k_fin: h0 rows for this batch group -> hs (same bits as old path)
    {
        int j = tid >> 4;                 // batch 0..15
        int ub = (tid & 15) * 32;         // unit base
        const float* prow = ps + (long)(b0 + j) * 1024;
#pragma unroll
        for (int q = 0; q < 4; q++) {
            float4 a  = *(const float4*)(prow + ub + q * 8);
            float4 b  = *(const float4*)(prow + ub + q * 8 + 4);
            float4 ba = *(const float4*)(bh + ub + q * 8);
            float4 bb = *(const float4*)(bh + ub + q * 8 + 4);
            unsigned short r[8] = {
                f2bf(tanhf(a.x + ba.x)), f2bf(tanhf(a.y + ba.y)),
                f2bf(tanhf(a.z + ba.z)), f2bf(tanhf(a.w + ba.w)),
                f2bf(tanhf(b.x + bb.x)), f2bf(tanhf(b.y + bb.y)),
                f2bf(tanhf(b.z + bb.z)), f2bf(tanhf(b.w + bb.w))};
            *(uint4*)&hs[j * 520 + ub + q * 8] = *(uint4*)r;
        }
    }
    // fused k_fin: c0 for own slice
    float c0v, c1v;
    {
        float2 pc  = *(const float2*)&ps[(long)(b0 + m) * 1024 + 512 + j0 + u0];
        float2 bcv = *(const float2*)&bc[j0 + u0];
        c0v = tanhf(pc.x + bcv.x);
        c1v = tanhf(pc.y + bcv.y);
    }
    int* ctr = ctrs + (gid & 3) * 64;
    __syncthreads();

    for (int s = 1; s < 64; s++) {
        // xg prefetch (read-only, normal cached loads)
        const float* xb = xg + ((long)(b0 + m) * 63 + (s - 1)) * 2048 + j0 + u0;
        float2 xv0 = *(const float2*)(xb + 0);
        float2 xv1 = *(const float2*)(xb + 512);
        float2 xv2 = *(const float2*)(xb + 1024);
        float2 xv3 = *(const float2*)(xb + 1536);

        if (s > 1) {
            // coherent staging of h[s-1]: 16 rows x 256 dwords, round j = row j
            const unsigned* hsrc = (const unsigned*)(Hbuf + ((long)(s - 1) * 64 + b0) * 512);
            unsigned hv[16];
#pragma unroll
            for (int j = 0; j < 16; j++)
                hv[j] = __hip_atomic_load(hsrc + j * 256 + tid, __ATOMIC_RELAXED,
                                          __HIP_MEMORY_SCOPE_AGENT);
#pragma unroll
            for (int j = 0; j < 16; j++)
                *(unsigned*)&hs[j * 520 + tid * 2] = hv[j];
        }
        __syncthreads();

        f32x4 acc0 = (f32x4){0.f, 0.f, 0.f, 0.f};
        f32x4 acc1 = (f32x4){0.f, 0.f, 0.f, 0.f};
#pragma unroll
        for (int kk = 0; kk < 16; kk++) {
            bf16x8 a  = *(const bf16x8*)&hs[l16 * 520 + kk * 32 + quad * 8];
            bf16x8 bA = *(const bf16x8*)&Wlds[(32 * w + l16) * 520 + kk * 32 + quad * 8];
            bf16x8 bB = *(const bf16x8*)&Wlds[(32 * w + 16 + l16) * 520 + kk * 32 + quad * 8];
            acc0 = __builtin_amdgcn_mfma_f32_16x16x32_bf16(a, bA, acc0, 0, 0, 0);
            acc1 = __builtin_amdgcn_mfma_f32_16x16x32_bf16(a, bB, acc1, 0, 0, 0);
        }
#pragma unroll
        for (int rr = 0; rr < 4; rr++) {
            gs[(quad * 4 + rr) * 133 + 32 * w + l16] = acc0[rr];
            gs[(quad * 4 + rr) * 133 + 32 * w + 16 + l16] = acc1[rr];
        }
        __syncthreads();

        float gi0 = gs[m * 133 + u0]          + xv0.x;
        float gi1 = gs[m * 133 + u0 + 1]      + xv0.y;
        float gf0 = gs[m * 133 + 32 + u0]     + xv1.x;
        float gf1 = gs[m * 133 + 33 + u0]     + xv1.y;
        float gg0 = gs[m * 133 + 64 + u0]     + xv2.x;
        float gg1 = gs[m * 133 + 65 + u0]     + xv2.y;
        float go0 = gs[m * 133 + 96 + u0]     + xv3.x;
        float go1 = gs[m * 133 + 97 + u0]     + xv3.y;
        float cn0 = (1.f / (1.f + __expf(-gf0))) * c0v + (1.f / (1.f + __expf(-gi0))) * tanhf(gg0);
        float cn1 = (1.f / (1.f + __expf(-gf1))) * c1v + (1.f / (1.f + __expf(-gi1))) * tanhf(gg1);
        c0v = cn0; c1v = cn1;
        float h0v = (1.f / (1.f + __expf(-go0))) * tanhf(cn0);
        float h1v = (1.f / (1.f + __expf(-go1))) * tanhf(cn1);
        unsigned hp = (unsigned)f2bf(h0v) | ((unsigned)f2bf(h1v) << 16);
        __hip_atomic_store((unsigned*)(Hbuf + ((long)s * 64 + b0 + m) * 512 + j0 + u0), hp,
                           __ATOMIC_RELAXED, __HIP_MEMORY_SCOPE_AGENT);

        if (s < 63) {
            __syncthreads();   // all waves' h stores drained (vmcnt 0) before count
            if (tid == 0) {
                __hip_atomic_fetch_add(ctr, 1, __ATOMIC_RELEASE, __HIP_MEMORY_SCOPE_AGENT);
                int target = s * 16;
                while (__hip_atomic_load(ctr, __ATOMIC_RELAXED, __HIP_MEMORY_SCOPE_AGENT) < target) {}
            }
            __syncthreads();
        }
    }
}

// ---------------- logits: R4-proven 128x128 tile + XCD n-major swizzle --------
__global__ __launch_bounds__(256) void k_out(
    const unsigned short* A, const unsigned short* Wob, const float* bout, float* out)
{
    __shared__ unsigned short As[128 * 32];
    __shared__ unsigned short Bs[128 * 32];
    const int tid = threadIdx.x;
    // 2528 tiles = 8 XCDs x 316; n-major within chunk: Wout panel L2-resident
    const int tile = (blockIdx.x & 7) * 316 + (blockIdx.x >> 3);
    const int n0 = (tile >> 5) * 128, m0 = (tile & 31) * 128;
    const int w = tid >> 6, lane = tid & 63, quad = lane >> 4, l16 = lane & 15;
    const int wm = w >> 1, wn = w & 1;
    const int gr = lane >> 2, gc = (lane & 3) * 8;

    f32x4 acc[4][4];
#pragma unroll
    for (int i = 0; i < 4; i++)
#pragma unroll
        for (int j = 0; j < 4; j++) acc[i][j] = (f32x4){0.f, 0.f, 0.f, 0.f};

    for (int kb = 0; kb < 16; kb++) {
        int k0 = kb * 32;
#pragma unroll
        for (int p = 0; p < 2; p++) {
            int rowa = m0 + p * 64 + w * 16 + gr;
            GLD_LDS16(A + (long)rowa * 512 + k0 + gc, As + (p * 64 + w * 16) * 32);
            int rowb = n0 + p * 64 + w * 16 + gr;
            GLD_LDS16(Wob + (long)rowb * 512 + k0 + gc, Bs + (p * 64 + w * 16) * 32);
        }
        __syncthreads();
        bf16x8 af[4], bf[4];
#pragma unroll
        for (int mt = 0; mt < 4; mt++)
            af[mt] = *(const bf16x8*)&As[(wm * 64 + mt * 16 + l16) * 32 + quad * 8];
#pragma unroll
        for (int nt = 0; nt < 4; nt++)
            bf[nt] = *(const bf16x8*)&Bs[(wn * 64 + nt * 16 + l16) * 32 + quad * 8];
#pragma unroll
        for (int mt = 0; mt < 4; mt++)
#pragma unroll
            for (int nt = 0; nt < 4; nt++)
                acc[mt][nt] = __builtin_amdgcn_mfma_f32_16x16x32_bf16(af[mt], bf[nt], acc[mt][nt], 0, 0, 0);
        __syncthreads();
    }
#pragma unroll
    for (int nt = 0; nt < 4; nt++) {
        int n = n0 + wn * 64 + nt * 16 + l16;
        if (n >= 10000) continue;
        float bias = bout[n];
#pragma unroll
        for (int mt = 0; mt < 4; mt++) {
#pragma unroll
            for (int rr = 0; rr < 4; rr++) {
                int r = m0 + wm * 64 + mt * 16 + quad * 4 + rr;  // A row
                if (r < 4032) {
                    int s = (r >> 6) + 1, b = r & 63;
                    out[((long)b * 64 + s) * 10000 + n] = acc[mt][nt][rr] + bias;
                }
            }
        }
    }
}

extern "C" void kernel_launch(void* const* d_in, const int* in_sizes, int n_in,
                              void* d_out, int out_size, void* d_ws, size_t ws_size,
                              hipStream_t stream)
{
    const float* enc     = (const float*)d_in[0];
    const int*   targets = (const int*)d_in[1];
    const float* emb     = (const float*)d_in[2];
    const float* Wih     = (const float*)d_in[3];
    const float* Whh     = (const float*)d_in[4];
    const float* bih     = (const float*)d_in[5];
    const float* bhh     = (const float*)d_in[6];
    const float* Wh      = (const float*)d_in[7];
    const float* bh      = (const float*)d_in[8];
    const float* Wc      = (const float*)d_in[9];
    const float* bc      = (const float*)d_in[10];
    const float* Wout    = (const float*)d_in[11];
    const float* bout    = (const float*)d_in[12];
    float* out = (float*)d_out;

    char* ws = (char*)d_ws;
    size_t off = 0;
    auto alloc = [&](size_t bytes) {
        void* p = ws + off;
        off = (off + bytes + 255) & ~(size_t)255;
        return p;
    };
    unsigned short* mean_b = (unsigned short*)alloc((size_t)64 * 2048 * 2);
    unsigned short* Wih_b  = (unsigned short*)alloc((size_t)2048 * 512 * 2);
    unsigned short* Whh_b  = (unsigned short*)alloc((size_t)2048 * 512 * 2);
    unsigned short* Wh_b   = (unsigned short*)alloc((size_t)512 * 2048 * 2);
    unsigned short* Wc_b   = (unsigned short*)alloc((size_t)512 * 2048 * 2);
    unsigned short* Wout_b = (unsigned short*)alloc((size_t)10000 * 512 * 2);
    // +64 pad rows: 128-row staging tiles overread past row 4032 harmlessly
    unsigned short* Aemb   = (unsigned short*)alloc((size_t)(4032 + 64) * 512 * 2);
    float*          xg     = (float*)alloc((size_t)4032 * 2048 * 4);
    // +64 pad rows: k_out's A view (Hbuf+64*512) staging reads up to row 4095
    unsigned short* Hbuf   = (unsigned short*)alloc((size_t)(64 * 64 + 64) * 512 * 2);
    int*            ctrs   = (int*)alloc(256 * 4);
    float*          ps     = (float*)alloc((size_t)64 * 1024 * 4);

    k_prep<<<3633, 256, 0, stream>>>(Wih, Whh, Wh, Wc, emb, targets, enc,
                                     Wih_b, Whh_b, Wh_b, Wc_b, Aemb,
                                     ctrs, ps, mean_b);
    k_gemm2<<<576, 256, 0, stream>>>(mean_b, Wh_b, Wc_b, ps,
                                     Aemb, Wih_b, bih, bhh, xg);
    // 64 scan blocks + 3125 shadow blocks (Wout cvt 2500, out zeros 625)
    k_scan<<<64 + 3125, 256, 0, stream>>>(Whh_b, xg, ps, bh, bc, Hbuf, ctrs,
                                          Wout, Wout_b, out);
    k_out<<<2528, 256, 0, stream>>>(Hbuf + 64 * 512, Wout_b, bout, out);
}